// Round 13
// baseline (203.503 us; speedup 1.0000x reference)
//
#include <hip/hip_runtime.h>
#include <hip/hip_fp16.h>
#include <cstdint>
#include <cmath>

#define QP    127.0f
#define MINR  1e-6f

// Problem dims: B*N = 8192 tokens, D = 1024, H = 4096
#define MTOK 8192
#define DDIM 1024
#define HDIM 4096

typedef __attribute__((ext_vector_type(4))) int int32x4;
typedef __attribute__((ext_vector_type(8))) short short8;

__device__ __forceinline__ void gload16(const void* g, void* l) {
    __builtin_amdgcn_global_load_lds(
        (const __attribute__((address_space(1))) void*)g,
        (__attribute__((address_space(3))) void*)l, 16, 0, 0);
}

__global__ void zero_scales_kernel(float* g) {
    if (threadIdx.x < 4) g[threadIdx.x] = 0.0f;
}

// ---- fused 3-tensor absmax: block-range partition, atomicMax per tensor ----
__device__ __forceinline__ float wave_block_max(float m) {
    #pragma unroll
    for (int off = 32; off; off >>= 1) m = fmaxf(m, __shfl_down(m, off));
    __shared__ float sm[4];
    int lane = threadIdx.x & 63, w = threadIdx.x >> 6;
    if (lane == 0) sm[w] = m;
    __syncthreads();
    float bm = 0.0f;
    if (threadIdx.x == 0) bm = fmaxf(fmaxf(sm[0], sm[1]), fmaxf(sm[2], sm[3]));
    return bm;
}

__device__ __forceinline__ void absmax_range(const float4* in4, int n4, int bid, int nb,
                                             float* gout) {
    int tid = bid * blockDim.x + threadIdx.x;
    int stride = nb * blockDim.x;
    float m = 0.0f;
    for (int i = tid; i < n4; i += stride) {
        float4 v = in4[i];
        m = fmaxf(m, fmaxf(fmaxf(fabsf(v.x), fabsf(v.y)), fmaxf(fabsf(v.z), fabsf(v.w))));
    }
    float bm = wave_block_max(m);
    if (threadIdx.x == 0) atomicMax((int*)gout, __float_as_int(bm));
}

// blocks [0,1024) -> x, [1024,1536) -> w1, [1536,2048) -> w2
__global__ void absmax3_kernel(const float* __restrict__ x, const float* __restrict__ w1,
                               const float* __restrict__ w2, float* __restrict__ gmax) {
    int b = blockIdx.x;
    if (b < 1024)      absmax_range((const float4*)x,  MTOK * DDIM / 4, b,        1024, gmax + 0);
    else if (b < 1536) absmax_range((const float4*)w1, HDIM * DDIM / 4, b - 1024,  512, gmax + 1);
    else               absmax_range((const float4*)w2, DDIM * HDIM / 4, b - 1536,  512, gmax + 3);
}

__device__ __forceinline__ void quant_range(const float4* in4, int* out4, int n4,
                                            int bid, int nb, const float* gm) {
    const float s = fmaxf(*gm, MINR) / QP;
    int tid = bid * blockDim.x + threadIdx.x;
    int stride = nb * blockDim.x;
    for (int i = tid; i < n4; i += stride) {
        float4 v = in4[i];
        int q0 = ((int)rintf(v.x / s)) & 255;
        int q1 = ((int)rintf(v.y / s)) & 255;
        int q2 = ((int)rintf(v.z / s)) & 255;
        int q3 = ((int)rintf(v.w / s)) & 255;
        out4[i] = q0 | (q1 << 8) | (q2 << 16) | (q3 << 24);
    }
}

// blocks [0,2048) -> x, [2048,3072) -> w1, [3072,4096) -> w2
__global__ void quant3_kernel(const float* __restrict__ x, const float* __restrict__ w1,
                              const float* __restrict__ w2, int8_t* __restrict__ xq,
                              int8_t* __restrict__ w1q, int8_t* __restrict__ w2q,
                              const float* __restrict__ gmax) {
    int b = blockIdx.x;
    if (b < 2048)      quant_range((const float4*)x,  (int*)xq,  MTOK * DDIM / 4, b,        2048, gmax + 0);
    else if (b < 3072) quant_range((const float4*)w1, (int*)w1q, HDIM * DDIM / 4, b - 2048, 1024, gmax + 1);
    else               quant_range((const float4*)w2, (int*)w2q, DDIM * HDIM / 4, b - 3072, 1024, gmax + 3);
}

// quantize h (fp16) -> int8.  8 halves per thread-iter (16B loads, 8B stores).
__global__ void quant_h_kernel(const __half* __restrict__ h, int8_t* __restrict__ hq,
                               const float* __restrict__ gm) {
    const float s = fmaxf(*gm, MINR) / QP;
    const short8* in8 = (const short8*)h;
    int2* out8 = (int2*)hq;
    const int n8 = MTOK * HDIM / 8;
    int tid = blockIdx.x * blockDim.x + threadIdx.x;
    int stride = gridDim.x * blockDim.x;
    for (int i = tid; i < n8; i += stride) {
        short8 v = in8[i];
        int q[8];
        #pragma unroll
        for (int j = 0; j < 8; ++j) {
            __half_raw r; r.x = (unsigned short)v[j];
            float f = __half2float(__half(r));
            q[j] = ((int)rintf(f / s)) & 255;
        }
        int2 o;
        o.x = q[0] | (q[1] << 8) | (q[2] << 16) | (q[3] << 24);
        o.y = q[4] | (q[5] << 8) | (q[6] << 16) | (q[7] << 24);
        out8[i] = o;
    }
}

// ---------------------------------------------------------------------------
// Round-13: exact m97-in-i8.  R7's proven loop with ONE variable changed:
// staging uses LINEAR lane->address mapping on both sides (no source
// pre-swizzle, no read XOR), A-gloads then B-gloads in monotonic order.
// Rationale: m97 (identical structure, bf16) measured ~14 TB/s global->LDS
// fill; all our swizzled-source kernels measured ~6.1 TB/s across 7 configs.
// Hypothesis: the (sl^(r&7)) source permutation crosses 64-B cachelines
// within each wave window and degrades TA coalescing ~2x.  Cost accepted:
// ds_reads become 16-way bank-conflicted (m97's own regime, 1.7e7 conflicts
// at 874 TF).  Fragment (row,k) math unchanged from the verified R1 mapping.
// ---------------------------------------------------------------------------
template<int KD, int ND, bool GELU_EPI, typename OUTT>
__global__ __launch_bounds__(256, 2)
void gemm_i8_kernel(const int8_t* __restrict__ A, const int8_t* __restrict__ B,
                    const float* __restrict__ bias,
                    const float* __restrict__ gmA, const float* __restrict__ gmB,
                    OUTT* __restrict__ out, float* __restrict__ omax) {
    constexpr int NBC = ND / 128;
    __shared__ int8_t lA[128 * 128];
    __shared__ int8_t lB[128 * 128];
    const int t = threadIdx.x;
    const int lane = t & 63;
    const int w = t >> 6;
    const int wm = (w >> 1) * 64;
    const int wn = (w & 1) * 64;
    const int lr = lane & 15;
    const int lg = lane >> 4;

    // R7's XCD transform (measured FETCH-positive): bc fastest in logical order
    const int chunk = gridDim.x >> 3;
    const int logical = (blockIdx.x & 7) * chunk + (blockIdx.x >> 3);
    const int bc = logical % NBC;
    const int br = logical / NBC;

    const int8_t* Ab = A + (size_t)br * 128 * KD;
    const int8_t* Bb = B + (size_t)bc * 128 * KD;

    int32x4 acc[4][4] = {};

    for (int kt = 0; kt < KD / 128; ++kt) {
        // LINEAR staging: chunk c -> LDS byte c*16; source row c>>3, col (c&7)*16.
        // Lane-monotonic addresses within each stream; A block then B block.
        #pragma unroll
        for (int i = 0; i < 4; ++i) {
            int c = t + i * 256;          // 0..1023
            gload16(Ab + (size_t)(c >> 3) * KD + kt * 128 + (c & 7) * 16, &lA[c * 16]);
        }
        #pragma unroll
        for (int i = 0; i < 4; ++i) {
            int c = t + i * 256;
            gload16(Bb + (size_t)(c >> 3) * KD + kt * 128 + (c & 7) * 16, &lB[c * 16]);
        }
        __syncthreads();

        #pragma unroll
        for (int kk = 0; kk < 2; ++kk) {
            int32x4 af[4], bf[4];
            #pragma unroll
            for (int m = 0; m < 4; ++m)
                af[m] = *(const int32x4*)&lA[(wm + m * 16 + lr) * 128 + (kk * 4 + lg) * 16];
            #pragma unroll
            for (int n = 0; n < 4; ++n)
                bf[n] = *(const int32x4*)&lB[(wn + n * 16 + lr) * 128 + (kk * 4 + lg) * 16];
            #pragma unroll
            for (int m = 0; m < 4; ++m)
                #pragma unroll
                for (int n = 0; n < 4; ++n)
                    acc[m][n] = __builtin_amdgcn_mfma_i32_16x16x64_i8(af[m], bf[n], acc[m][n], 0, 0, 0);
        }
        __syncthreads();
    }

    // epilogue — replicate reference fp32 op order exactly; absmax from the
    // full-precision fp32 value (scale semantics preserved for fp16 h out)
    const float sA = fmaxf(*gmA, MINR) / QP;
    const float sB = fmaxf(*gmB, MINR) / QP;
    const float s = sB * sA;
    float lmax = 0.0f;
    #pragma unroll
    for (int m = 0; m < 4; ++m) {
        #pragma unroll
        for (int n = 0; n < 4; ++n) {
            #pragma unroll
            for (int r = 0; r < 4; ++r) {
                int row = br * 128 + wm + m * 16 + lg * 4 + r;
                int col = bc * 128 + wn + n * 16 + lr;
                float f = (float)acc[m][n][r] + bias[col];
                f *= s;
                if (GELU_EPI) {
                    float gg = f * (erff(f / 1.41421356237309504880f) + 1.0f) * 0.5f;
                    out[(size_t)row * ND + col] = (OUTT)gg;
                    lmax = fmaxf(lmax, fabsf(gg));
                } else {
                    out[(size_t)row * ND + col] = (OUTT)f;
                }
            }
        }
    }
    if (GELU_EPI) {
        #pragma unroll
        for (int off = 32; off; off >>= 1) lmax = fmaxf(lmax, __shfl_down(lmax, off));
        __shared__ float red[4];
        if (lane == 0) red[w] = lmax;
        __syncthreads();
        if (t == 0) {
            float bm = fmaxf(fmaxf(red[0], red[1]), fmaxf(red[2], red[3]));
            atomicMax((int*)omax, __float_as_int(bm));
        }
    }
}

extern "C" void kernel_launch(void* const* d_in, const int* in_sizes, int n_in,
                              void* d_out, int out_size, void* d_ws, size_t ws_size,
                              hipStream_t stream) {
    const float* x  = (const float*)d_in[0];   // [8192, 1024]
    const float* w1 = (const float*)d_in[1];   // [4096, 1024]
    const float* b1 = (const float*)d_in[2];   // [4096]
    const float* w2 = (const float*)d_in[3];   // [1024, 4096]
    const float* b2 = (const float*)d_in[4];   // [1024]
    float* out = (float*)d_out;                // [8192, 1024]

    uint8_t* ws = (uint8_t*)d_ws;
    float*  gmax = (float*)ws;                           // [0]=x [1]=w1 [2]=h [3]=w2
    int8_t* xq   = (int8_t*)(ws + 256);                  // 8 MiB
    int8_t* w1q  = xq  + (size_t)MTOK * DDIM;            // 4 MiB
    int8_t* w2q  = w1q + (size_t)HDIM * DDIM;            // 4 MiB
    int8_t* hq   = w2q + (size_t)DDIM * HDIM;            // 32 MiB
    __half* h    = (__half*)(hq + (size_t)MTOK * HDIM);  // 64 MiB fp16

    zero_scales_kernel<<<1, 64, 0, stream>>>(gmax);

    absmax3_kernel<<<2048, 256, 0, stream>>>(x, w1, w2, gmax);
    quant3_kernel<<<4096, 256, 0, stream>>>(x, w1, w2, xq, w1q, w2q, gmax);

    // h(fp16) = gelu((xq @ w1q^T + b1) * s1), fused fp32 absmax(h) -> gmax[2]
    // grid = 2048 (%8==0)
    gemm_i8_kernel<DDIM, HDIM, true, __half>
        <<<2048, 256, 0, stream>>>(xq, w1q, b1, gmax + 0, gmax + 1, h, gmax + 2);

    quant_h_kernel<<<2048, 256, 0, stream>>>(h, hq, gmax + 2);

    // out = (hq @ w2q^T + b2) * s2 ; grid = 512 (%8==0)
    gemm_i8_kernel<HDIM, DDIM, false, float>
        <<<512, 256, 0, stream>>>(hq, w2q, b2, gmax + 2, gmax + 3, out, nullptr);
}